// Round 18
// baseline (306.849 us; speedup 1.0000x reference)
//
#include <hip/hip_runtime.h>
#include <hip/hip_bf16.h>
#include <cstdint>
#include <cstddef>

// Problem constants (match reference)
#define N_NODES  20000
#define N_EDGES  320000
#define E_TOTAL  (N_EDGES + N_NODES)   // with self loops = 340000
#define N_GRAPHS 256
#define F_NODE   11
#define F_TDA    30
#define DIM      128
#define NHEAD    4
#define NLAYER   3
#define NTASK    6
#define NEG_SLOPE 0.2f
#define LN_EPS   1e-5f
#define CSR_CAP  64   // fixed per-node capacity; deg ~ Poisson(17), P(>64) ~ 0

typedef short bf16x8 __attribute__((ext_vector_type(8)));
typedef float f32x4  __attribute__((ext_vector_type(4)));
typedef float f32x2  __attribute__((ext_vector_type(2)));

__device__ inline unsigned short f2b(float f) {
    unsigned int u = __builtin_bit_cast(unsigned int, f);
    u += 0x7fffu + ((u >> 16) & 1u);
    return (unsigned short)(u >> 16);
}
__device__ inline float blo(unsigned int u) { return __builtin_bit_cast(float, u << 16); }
__device__ inline float bhi(unsigned int u) { return __builtin_bit_cast(float, u & 0xffff0000u); }
__device__ inline float b2f(unsigned short b) {
    return __builtin_bit_cast(float, ((unsigned int)b) << 16);
}

// ---------------------------------------------------------------------------
// qprep: [0,768) Wstack cast (k-permuted, 0.25 folded); [768,1152) q vectors;
// [1152,1172) zero degs. Runs BEFORE prep so prep can read q_s/q_d safely.
// z layout: p = lane*8 + h*2 + b, logical feature d = 2*lane+b.
// ---------------------------------------------------------------------------
__global__ __launch_bounds__(256) void qprep_kernel(const float* __restrict__ w_gat,
                                                    const float* __restrict__ a_src,
                                                    const float* __restrict__ a_dst,
                                                    unsigned short* __restrict__ wt2,
                                                    float* __restrict__ q_s,
                                                    float* __restrict__ q_d,
                                                    int* __restrict__ degs) {
    int bx = blockIdx.x;
    int tid = threadIdx.x;
    if (bx < 768) {
        int i = bx * 256 + tid;              // over 3*128*512
        if (i >= NLAYER * 128 * 512) return;
        int l = i >> 16;
        int rem = i & 65535;
        int jcol = rem >> 9;
        int p = rem & 511;
        int lanep = p >> 3, j8 = p & 7;
        int hp = j8 >> 1, bb = j8 & 1;
        int d = lanep * 2 + bb;
        wt2[i] = f2b(w_gat[(size_t)l * 65536 + (size_t)d * 512 + hp * 128 + jcol] * 0.25f);
    } else if (bx < 1152) {
        int bx2 = bx - 768;                  // over 3*128
        int l = bx2 >> 7, k = bx2 & 127;
        int hh_ = tid >> 6, lane = tid & 63;
        int d0 = lane * 2;
        size_t wb = (size_t)l * 65536 + (size_t)k * 512 + hh_ * 128;
        size_t ab = (size_t)l * 512 + hh_ * 128;
        float ps = w_gat[wb + d0] * a_src[ab + d0] + w_gat[wb + d0 + 1] * a_src[ab + d0 + 1];
        float pd = w_gat[wb + d0] * a_dst[ab + d0] + w_gat[wb + d0 + 1] * a_dst[ab + d0 + 1];
#pragma unroll
        for (int off = 32; off; off >>= 1) { ps += __shfl_xor(ps, off); pd += __shfl_xor(pd, off); }
        if (lane == 0) {
            q_s[(size_t)(l * 128 + k) * 4 + hh_] = ps;
            q_d[(size_t)(l * 128 + k) * 4 + hh_] = pd;
        }
    } else {
        int i0 = (bx - 1152) * 1024 + tid;
#pragma unroll
        for (int r = 0; r < 4; r++) {
            int i = i0 + r * 256;
            if (i < N_NODES) degs[i] = 0;
        }
    }
}

// ---------------------------------------------------------------------------
// prep: [0,2500) fat projection (8 nodes/block) + layer-0 alpha;
//       [2500, +333) fixed-capacity CSR scatter, 4 edges/thread.
// ---------------------------------------------------------------------------
__global__ __launch_bounds__(256) void prep_kernel(const float* __restrict__ x,
                                                   const float* __restrict__ w,
                                                   const float* __restrict__ b,
                                                   unsigned short* __restrict__ h_bf,
                                                   const float* __restrict__ q_s,
                                                   const float* __restrict__ q_d,
                                                   float4* __restrict__ als4,
                                                   float4* __restrict__ ald4,
                                                   const int* __restrict__ edge_index,
                                                   int* __restrict__ degs,
                                                   int* __restrict__ csr_src) {
    int bx = blockIdx.x;
    int tid = threadIdx.x;
    if (bx < 2500) {
        __shared__ float xr[8][F_NODE];
        __shared__ float vbuf[8][128];
        __shared__ float qs_t[512];
        __shared__ float qd_t[512];
        qs_t[tid] = q_s[tid]; qs_t[256 + tid] = q_s[256 + tid];
        qd_t[tid] = q_d[tid]; qd_t[256 + tid] = q_d[256 + tid];
        if (tid < 8 * F_NODE) {
            int nl = tid / F_NODE, k = tid % F_NODE;
            xr[nl][k] = x[(size_t)(bx * 8 + nl) * F_NODE + k];
        }
        __syncthreads();
        int d = tid & 127;
        int halfsel = tid >> 7;
#pragma unroll
        for (int p = 0; p < 4; p++) {
            int nl = p * 2 + halfsel;
            float acc = b[d];
#pragma unroll
            for (int k = 0; k < F_NODE; k++) acc += xr[nl][k] * w[k * DIM + d];
            float v = fmaxf(acc, 0.f);
            h_bf[(size_t)(bx * 8 + nl) * DIM + d] = f2b(v);
            vbuf[nl][d] = v;
        }
        __syncthreads();
        int wave = tid >> 6, lane = tid & 63;
#pragma unroll
        for (int t = 0; t < 2; t++) {
            int nl = wave * 2 + t;
            int n = bx * 8 + nl;
            float2 v2 = *(const float2*)&vbuf[nl][2 * lane];
            int k4 = 2 * lane * 4;
            float ps[4], pd[4];
#pragma unroll
            for (int hh_ = 0; hh_ < 4; hh_++) {
                ps[hh_] = v2.x * qs_t[k4 + hh_] + v2.y * qs_t[k4 + 4 + hh_];
                pd[hh_] = v2.x * qd_t[k4 + hh_] + v2.y * qd_t[k4 + 4 + hh_];
            }
#pragma unroll
            for (int off = 32; off; off >>= 1) {
#pragma unroll
                for (int hh_ = 0; hh_ < 4; hh_++) {
                    ps[hh_] += __shfl_xor(ps[hh_], off);
                    pd[hh_] += __shfl_xor(pd[hh_], off);
                }
            }
            if (lane == 0) {
                als4[n] = make_float4(ps[0], ps[1], ps[2], ps[3]);
                ald4[n] = make_float4(pd[0], pd[1], pd[2], pd[3]);
            }
        }
    } else {
        int base = (bx - 2500) * 1024;
#pragma unroll
        for (int k = 0; k < 4; k++) {
            int e = base + k * 256 + tid;
            if (e < E_TOTAL) {
                int s, d;
                if (e < N_EDGES) { s = edge_index[e]; d = edge_index[N_EDGES + e]; }
                else             { s = e - N_EDGES;   d = s; }
                int pos = atomicAdd(&degs[d], 1);
                if (pos < CSR_CAP) csr_src[d * CSR_CAP + pos] = s;
            }
        }
    }
}

// ---------------------------------------------------------------------------
// h-space aggregation, software-pipelined (ping-pong A/B gather buffers):
// batch b+1's index loads + hh gathers + alpha load are issued BEFORE batch
// b's compute, so memory latency overlaps VALU work. Wave per node; lane owns
// feature pair (2*lane, 2*lane+1) for all 4 heads; exp dedup via readlane.
// z layout: p = lane*8 + h*2 + b (uint4 store per lane).
// ---------------------------------------------------------------------------
template<int LYR>
__global__ __launch_bounds__(256) void agg2_kernel(const unsigned short* __restrict__ h_bf,
                                                   const float4* __restrict__ als4,
                                                   const float4* __restrict__ ald4,
                                                   const int* __restrict__ degs,
                                                   const int* __restrict__ csr_src,
                                                   unsigned short* __restrict__ z) {
    int wave = threadIdx.x >> 6, lane = threadIdx.x & 63;
    int n = blockIdx.x * 4 + wave;
    if (n >= N_NODES) return;

    int deg = degs[n];
    const int* __restrict__ srcp = csr_src + (size_t)n * CSR_CAP;
    const unsigned int* __restrict__ h32 = (const unsigned int*)h_bf;
    const float* __restrict__ als_f = (const float*)als4;
    float4 ad = ald4[n];

    int l4 = lane & 3;                   // head this lane's w-computation covers
    int le = (lane >> 2) & 3;            // edge-in-batch this lane covers
    float adh = (l4 == 0) ? ad.x : ((l4 == 1) ? ad.y : ((l4 == 2) ? ad.z : ad.w));

    f32x2 acc2[4] = {};
    float lsOwn = 0.f;

    int nb = deg >> 2;                   // full 4-edge batches
    unsigned int hA[4], hB[4];
    float aA = 0.f, aB = 0.f;

    if (nb >= 1) {
        int sA[4];
#pragma unroll
        for (int j = 0; j < 4; j++) sA[j] = srcp[j];
#pragma unroll
        for (int j = 0; j < 4; j++) hA[j] = h32[(size_t)sA[j] * 64 + lane];
        aA = als_f[(size_t)sA[le] * 4 + l4];
    }
    for (int b = 0; b < nb; b++) {
        if ((b & 1) == 0) {
            if (b + 1 < nb) {            // issue batch b+1 loads (into B) first
                int sB[4];
#pragma unroll
                for (int j = 0; j < 4; j++) sB[j] = srcp[(b + 1) * 4 + j];
#pragma unroll
                for (int j = 0; j < 4; j++) hB[j] = h32[(size_t)sB[j] * 64 + lane];
                aB = als_f[(size_t)sB[le] * 4 + l4];
            }
            float v = aA + adh;
            v = fmaxf(v, NEG_SLOPE * v);
            float w = __expf(fminf(v, 60.f));
            lsOwn += w;
            float wv[16];
#pragma unroll
            for (int j = 0; j < 16; j++) wv[j] = __shfl(w, j);
#pragma unroll
            for (int j = 0; j < 4; j++) {
                f32x2 f; f.x = blo(hA[j]); f.y = bhi(hA[j]);
                acc2[0] += wv[j * 4 + 0] * f;
                acc2[1] += wv[j * 4 + 1] * f;
                acc2[2] += wv[j * 4 + 2] * f;
                acc2[3] += wv[j * 4 + 3] * f;
            }
        } else {
            if (b + 1 < nb) {            // issue batch b+1 loads (into A) first
                int sA[4];
#pragma unroll
                for (int j = 0; j < 4; j++) sA[j] = srcp[(b + 1) * 4 + j];
#pragma unroll
                for (int j = 0; j < 4; j++) hA[j] = h32[(size_t)sA[j] * 64 + lane];
                aA = als_f[(size_t)sA[le] * 4 + l4];
            }
            float v = aB + adh;
            v = fmaxf(v, NEG_SLOPE * v);
            float w = __expf(fminf(v, 60.f));
            lsOwn += w;
            float wv[16];
#pragma unroll
            for (int j = 0; j < 16; j++) wv[j] = __shfl(w, j);
#pragma unroll
            for (int j = 0; j < 4; j++) {
                f32x2 f; f.x = blo(hB[j]); f.y = bhi(hB[j]);
                acc2[0] += wv[j * 4 + 0] * f;
                acc2[1] += wv[j * 4 + 1] * f;
                acc2[2] += wv[j * 4 + 2] * f;
                acc2[3] += wv[j * 4 + 3] * f;
            }
        }
    }
    float ls[4];
#pragma unroll
    for (int hh_ = 0; hh_ < 4; hh_++) {
        ls[hh_] = __shfl(lsOwn, hh_) + __shfl(lsOwn, 4 + hh_)
                + __shfl(lsOwn, 8 + hh_) + __shfl(lsOwn, 12 + hh_);
    }
    for (int e = nb << 2; e < deg; e++) {
        int s = srcp[e];
        float4 a4 = als4[s];
        unsigned int vv = h32[(size_t)s * 64 + lane];
        f32x2 f; f.x = blo(vv); f.y = bhi(vv);
#pragma unroll
        for (int hh_ = 0; hh_ < 4; hh_++) {
            float v = (&a4.x)[hh_] + (&ad.x)[hh_];
            v = (v > 0.f) ? v : NEG_SLOPE * v;
            float w = __expf(fminf(v, 60.f));
            ls[hh_] += w;
            acc2[hh_] += w * f;
        }
    }
    uint4 pb;
    unsigned int* pc = &pb.x;
#pragma unroll
    for (int hh_ = 0; hh_ < 4; hh_++) {
        float il = 1.f / ls[hh_];
        pc[hh_] = (unsigned)f2b(acc2[hh_].x * il) | ((unsigned)f2b(acc2[hh_].y * il) << 16);
    }
    *(uint4*)(z + (size_t)n * 512 + lane * 8) = pb;
}

// ---------------------------------------------------------------------------
// zgemm (templated per layer): out = z[M,512] @ wt2[128,512]^T, fused bias +
// LN + ReLU + bf16 residual + next-layer alpha. 64x128 tile, K in 4 chunks.
// ---------------------------------------------------------------------------
template<int LYR>
__global__ __launch_bounds__(256) void zgemm_kernel(const unsigned short* __restrict__ z,
                                                    const unsigned short* __restrict__ wt2_l,
                                                    const float* __restrict__ b_gat,
                                                    const float* __restrict__ ln_w,
                                                    const float* __restrict__ ln_b,
                                                    const unsigned short* __restrict__ hb_in,
                                                    unsigned short* __restrict__ hb_out,
                                                    const float* __restrict__ q_s_next,
                                                    const float* __restrict__ q_d_next,
                                                    float4* __restrict__ als4,
                                                    float4* __restrict__ ald4,
                                                    int M) {
    __shared__ __align__(16) unsigned short As[64 * 136];
    __shared__ __align__(16) unsigned short Bs[128 * 136];
    int tid = threadIdx.x;
    int m0 = blockIdx.x << 6;
    int wave = tid >> 6, lane = tid & 63;
    int lr = lane & 15, lg = lane >> 4;

    const uint4 zero4 = make_uint4(0, 0, 0, 0);
    f32x4 acc[8] = {};
    for (int kc = 0; kc < 4; kc++) {
#pragma unroll
        for (int p = 0; p < 4; p++) {        // A: 64 rows x 16 kg
            int i = p * 256 + tid;
            int row = i >> 4, kg = i & 15;
            int arow = m0 + row;
            uint4 av = (arow < M) ? *(const uint4*)(z + (size_t)arow * 512 + kc * 128 + kg * 8) : zero4;
            *(uint4*)&As[row * 136 + kg * 8] = av;
        }
#pragma unroll
        for (int p = 0; p < 8; p++) {        // B: 128 rows x 16 kg
            int i = p * 256 + tid;
            int row = i >> 4, kg = i & 15;
            uint4 bv = *(const uint4*)(wt2_l + (size_t)row * 512 + kc * 128 + kg * 8);
            *(uint4*)&Bs[row * 136 + kg * 8] = bv;
        }
        __syncthreads();
#pragma unroll
        for (int ks = 0; ks < 4; ks++) {
            bf16x8 af = *(const bf16x8*)&As[(wave * 16 + lr) * 136 + ks * 32 + lg * 8];
#pragma unroll
            for (int nt = 0; nt < 8; nt++) {
                bf16x8 bf_ = *(const bf16x8*)&Bs[(nt * 16 + lr) * 136 + ks * 32 + lg * 8];
                acc[nt] = __builtin_amdgcn_mfma_f32_16x16x32_bf16(af, bf_, acc[nt], 0, 0, 0);
            }
        }
        __syncthreads();
    }

    // epilogue: bias + LN + relu + residual (+ next-layer alpha)
    float bg[8], lnw[8], lnb[8];
#pragma unroll
    for (int nt = 0; nt < 8; nt++) {
        int col = nt * 16 + lr;
        bg[nt] = b_gat[col]; lnw[nt] = ln_w[col]; lnb[nt] = ln_b[col];
    }
    const bool do_alpha = (LYR + 1 < NLAYER);
    float4 qs4[8], qd4[8];
    if (do_alpha) {
#pragma unroll
        for (int nt = 0; nt < 8; nt++) {
            int col = nt * 16 + lr;
            qs4[nt] = *(const float4*)(q_s_next + (size_t)col * 4);
            qd4[nt] = *(const float4*)(q_d_next + (size_t)col * 4);
        }
    }
#pragma unroll
    for (int r = 0; r < 4; r++) {
        int row = m0 + wave * 16 + lg * 4 + r;
        bool valid = (row < M);
        float g[8];
        float s = 0.f;
#pragma unroll
        for (int nt = 0; nt < 8; nt++) { g[nt] = acc[nt][r] + bg[nt]; s += g[nt]; }
#pragma unroll
        for (int off = 1; off < 16; off <<= 1) s += __shfl_xor(s, off);
        float mu = s * (1.f / 128.f);
        float s2 = 0.f;
#pragma unroll
        for (int nt = 0; nt < 8; nt++) { float d = g[nt] - mu; s2 += d * d; }
#pragma unroll
        for (int off = 1; off < 16; off <<= 1) s2 += __shfl_xor(s2, off);
        float rstd = rsqrtf(s2 * (1.f / 128.f) + LN_EPS);
        float o[8];
#pragma unroll
        for (int nt = 0; nt < 8; nt++) {
            int col = nt * 16 + lr;
            float hv = valid ? b2f(hb_in[(size_t)row * 128 + col]) : 0.f;
            o[nt] = fmaxf((g[nt] - mu) * rstd * lnw[nt] + lnb[nt], 0.f) + hv;
            if (valid) hb_out[(size_t)row * 128 + col] = f2b(o[nt]);
        }
        if (do_alpha) {
            float ps[4] = {}, pd[4] = {};
#pragma unroll
            for (int nt = 0; nt < 8; nt++) {
                ps[0] += o[nt] * qs4[nt].x; pd[0] += o[nt] * qd4[nt].x;
                ps[1] += o[nt] * qs4[nt].y; pd[1] += o[nt] * qd4[nt].y;
                ps[2] += o[nt] * qs4[nt].z; pd[2] += o[nt] * qd4[nt].z;
                ps[3] += o[nt] * qs4[nt].w; pd[3] += o[nt] * qd4[nt].w;
            }
#pragma unroll
            for (int off = 1; off < 16; off <<= 1) {
#pragma unroll
                for (int hh_ = 0; hh_ < 4; hh_++) {
                    ps[hh_] += __shfl_xor(ps[hh_], off);
                    pd[hh_] += __shfl_xor(pd[hh_], off);
                }
            }
            if (lr == 0 && valid) {
                als4[row] = make_float4(ps[0], ps[1], ps[2], ps[3]);
                ald4[row] = make_float4(pd[0], pd[1], pd[2], pd[3]);
            }
        }
    }
}

// ---------------------------------------------------------------------------
// Fused pooling + tail per graph (h is bf16).
// ---------------------------------------------------------------------------
__device__ int lower_bound_dev(const int* a, int n, int v) {
    int lo = 0, hi = n;
    while (lo < hi) { int mid = (lo + hi) >> 1; if (a[mid] < v) lo = mid + 1; else hi = mid; }
    return lo;
}

__global__ __launch_bounds__(512) void pooltail_kernel(
    const unsigned short* __restrict__ h, const int* __restrict__ batch,
    const float* __restrict__ tda,
    const float* __restrict__ w_t1, const float* __restrict__ b_t1,
    const float* __restrict__ w_t2, const float* __restrict__ b_t2,
    const float* __restrict__ w_sh1, const float* __restrict__ b_sh1,
    const float* __restrict__ w_sh2, const float* __restrict__ b_sh2,
    const float* __restrict__ w_h1, const float* __restrict__ b_h1,
    const float* __restrict__ w_h2, const float* __restrict__ b_h2,
    float* __restrict__ out) {
    __shared__ float ssum[4][128];
    __shared__ float smax[4][128];
    __shared__ int bounds[2];
    __shared__ float comb[320];
    __shared__ float tr[F_TDA];
    __shared__ float t1[64];
    __shared__ float s1o[256];
    __shared__ float s2o[128];
    __shared__ float prods[NTASK * 64];
    int g = blockIdx.x, tid = threadIdx.x;

    if (tid < 2) bounds[tid] = lower_bound_dev(batch, N_NODES, g + tid);
    if (tid >= 2 && tid - 2 < F_TDA) tr[tid - 2] = tda[g * F_TDA + (tid - 2)];
    __syncthreads();
    int lo = bounds[0], hi = bounds[1];
    int q = tid >> 7, d = tid & 127;
    float s = 0.f, m = -1e30f;
    for (int i = lo + q; i < hi; i += 4) {
        float v = b2f(h[(size_t)i * DIM + d]);
        s += v; m = fmaxf(m, v);
    }
    ssum[q][d] = s; smax[q][d] = m;
    __syncthreads();
    if (tid < 128) {
        float S = ssum[0][d] + ssum[1][d] + ssum[2][d] + ssum[3][d];
        float M = fmaxf(fmaxf(smax[0][d], smax[1][d]), fmaxf(smax[2][d], smax[3][d]));
        int cnt = hi - lo;
        comb[d] = S / fmaxf((float)cnt, 1.f);
        comb[128 + d] = (cnt > 0) ? M : 0.f;
    } else if (tid >= 128 && tid < 192) {
        int j = tid - 128;
        float a = b_t1[j];
#pragma unroll
        for (int k = 0; k < F_TDA; k++) a += tr[k] * w_t1[k * 64 + j];
        t1[j] = fmaxf(a, 0.f);
    }
    __syncthreads();
    if (tid < 64) {
        float a = b_t2[tid];
#pragma unroll
        for (int k = 0; k < 64; k++) a += t1[k] * w_t2[k * 64 + tid];
        comb[256 + tid] = fmaxf(a, 0.f);
    }
    __syncthreads();
    if (tid < 256) {
        float a = b_sh1[tid];
        for (int k = 0; k < 320; k++) a += comb[k] * w_sh1[k * 256 + tid];
        s1o[tid] = fmaxf(a, 0.f);
    }
    __syncthreads();
    if (tid < 128) {
        float a = b_sh2[tid];
        for (int k = 0; k < 256; k++) a += s1o[k] * w_sh2[k * 128 + tid];
        s2o[tid] = fmaxf(a, 0.f);
    }
    __syncthreads();
    if (tid < NTASK * 64) {
        int t = tid >> 6, k = tid & 63;
        float a = b_h1[t * 64 + k];
#pragma unroll 16
        for (int dd = 0; dd < 128; dd++) a += s2o[dd] * w_h1[(size_t)t * 8192 + dd * 64 + k];
        prods[tid] = fmaxf(a, 0.f) * w_h2[t * 64 + k];
    }
    __syncthreads();
    if (tid < NTASK) {
        float p = b_h2[tid];
#pragma unroll 16
        for (int k = 0; k < 64; k++) p += prods[tid * 64 + k];
        out[tid * 256 + g] = p;
    }
}

// ---------------------------------------------------------------------------
extern "C" void kernel_launch(void* const* d_in, const int* in_sizes, int n_in,
                              void* d_out, int out_size, void* d_ws, size_t ws_size,
                              hipStream_t stream) {
    const float* x        = (const float*)d_in[0];
    const int*   edge_idx = (const int*)  d_in[1];
    const int*   batch    = (const int*)  d_in[2];
    const float* tda      = (const float*)d_in[3];
    const float* w_in     = (const float*)d_in[4];
    const float* b_in     = (const float*)d_in[5];
    const float* w_gat    = (const float*)d_in[6];
    const float* a_src    = (const float*)d_in[7];
    const float* a_dst    = (const float*)d_in[8];
    const float* b_gat    = (const float*)d_in[9];
    const float* ln_w     = (const float*)d_in[10];
    const float* ln_b     = (const float*)d_in[11];
    const float* w_tda1   = (const float*)d_in[12];
    const float* b_tda1   = (const float*)d_in[13];
    const float* w_tda2   = (const float*)d_in[14];
    const float* b_tda2   = (const float*)d_in[15];
    const float* w_sh1    = (const float*)d_in[16];
    const float* b_sh1    = (const float*)d_in[17];
    const float* w_sh2    = (const float*)d_in[18];
    const float* b_sh2    = (const float*)d_in[19];
    const float* w_h1     = (const float*)d_in[20];
    const float* b_h1     = (const float*)d_in[21];
    const float* w_h2     = (const float*)d_in[22];
    const float* b_h2     = (const float*)d_in[23];
    float* out = (float*)d_out;

    size_t off = 0;
    auto alloc = [&](size_t bytes) -> void* {
        void* p = (char*)d_ws + off;
        off += (bytes + 255) & ~(size_t)255;
        return p;
    };
    unsigned short* hb_a   = (unsigned short*)alloc((size_t)N_NODES * DIM * 2);
    unsigned short* hb_b   = (unsigned short*)alloc((size_t)N_NODES * DIM * 2);
    unsigned short* z      = (unsigned short*)alloc((size_t)N_NODES * 512 * 2);
    unsigned short* wt2    = (unsigned short*)alloc((size_t)NLAYER * 128 * 512 * 2);
    float*          q_s    = (float*)alloc((size_t)NLAYER * 128 * 4 * 4);
    float*          q_d    = (float*)alloc((size_t)NLAYER * 128 * 4 * 4);
    float4*         als4   = (float4*)alloc((size_t)N_NODES * 16);
    float4*         ald4   = (float4*)alloc((size_t)N_NODES * 16);
    int*            degs   = (int*)  alloc((size_t)N_NODES * 4);
    int*            csrsrc = (int*)  alloc((size_t)N_NODES * CSR_CAP * 4);

    // qprep also zeroes degs (blocks 1152..1171) — no separate memset
    qprep_kernel<<<1172, 256, 0, stream>>>(w_gat, a_src, a_dst, wt2, q_s, q_d, degs);

    int sb = (E_TOTAL + 1023) / 1024;   // 333
    prep_kernel<<<2500 + sb, 256, 0, stream>>>(x, w_in, b_in, hb_a, q_s, q_d,
                                               als4, ald4, edge_idx, degs, csrsrc);

    int ab = (N_NODES + 3) / 4;
    int gb = (N_NODES + 63) / 64;
    // layer 0: hb_a -> hb_b
    agg2_kernel<0><<<ab, 256, 0, stream>>>(hb_a, als4, ald4, degs, csrsrc, z);
    zgemm_kernel<0><<<gb, 256, 0, stream>>>(z, wt2,
        b_gat, ln_w, ln_b, hb_a, hb_b, q_s + 512, q_d + 512, als4, ald4, N_NODES);
    // layer 1: hb_b -> hb_a
    agg2_kernel<1><<<ab, 256, 0, stream>>>(hb_b, als4, ald4, degs, csrsrc, z);
    zgemm_kernel<1><<<gb, 256, 0, stream>>>(z, wt2 + 65536,
        b_gat + DIM, ln_w + DIM, ln_b + DIM, hb_b, hb_a, q_s + 1024, q_d + 1024,
        als4, ald4, N_NODES);
    // layer 2: hb_a -> hb_b
    agg2_kernel<2><<<ab, 256, 0, stream>>>(hb_a, als4, ald4, degs, csrsrc, z);
    zgemm_kernel<2><<<gb, 256, 0, stream>>>(z, wt2 + 131072,
        b_gat + 2 * DIM, ln_w + 2 * DIM, ln_b + 2 * DIM, hb_a, hb_b,
        nullptr, nullptr, als4, ald4, N_NODES);

    pooltail_kernel<<<N_GRAPHS, 512, 0, stream>>>(
        hb_b, batch, tda, w_tda1, b_tda1, w_tda2, b_tda2,
        w_sh1, b_sh1, w_sh2, b_sh2, w_h1, b_h1, w_h2, b_h2, out);
}

// Round 19
// 293.555 us; speedup vs baseline: 1.0453x; 1.0453x over previous
//
#include <hip/hip_runtime.h>
#include <hip/hip_bf16.h>
#include <cstdint>
#include <cstddef>

// Problem constants (match reference)
#define N_NODES  20000
#define N_EDGES  320000
#define E_TOTAL  (N_EDGES + N_NODES)   // with self loops = 340000
#define N_GRAPHS 256
#define F_NODE   11
#define F_TDA    30
#define DIM      128
#define NHEAD    4
#define NLAYER   3
#define NTASK    6
#define NEG_SLOPE 0.2f
#define LN_EPS   1e-5f
#define CSR_CAP  64   // fixed per-node capacity; deg ~ Poisson(17), P(>64) ~ 0

typedef short bf16x8 __attribute__((ext_vector_type(8)));
typedef float f32x4  __attribute__((ext_vector_type(4)));
typedef float f32x2  __attribute__((ext_vector_type(2)));

__device__ inline unsigned short f2b(float f) {
    unsigned int u = __builtin_bit_cast(unsigned int, f);
    u += 0x7fffu + ((u >> 16) & 1u);
    return (unsigned short)(u >> 16);
}
__device__ inline float blo(unsigned int u) { return __builtin_bit_cast(float, u << 16); }
__device__ inline float bhi(unsigned int u) { return __builtin_bit_cast(float, u & 0xffff0000u); }
__device__ inline float b2f(unsigned short b) {
    return __builtin_bit_cast(float, ((unsigned int)b) << 16);
}

// ---------------------------------------------------------------------------
// qprep: [0,768) Wstack cast (k-permuted, 0.25 folded); [768,1152) q vectors;
// [1152,1172) zero degs. Runs BEFORE prep so prep can read q_s/q_d safely.
// z layout: p = lane*8 + h*2 + b, logical feature d = 2*lane+b.
// ---------------------------------------------------------------------------
__global__ __launch_bounds__(256) void qprep_kernel(const float* __restrict__ w_gat,
                                                    const float* __restrict__ a_src,
                                                    const float* __restrict__ a_dst,
                                                    unsigned short* __restrict__ wt2,
                                                    float* __restrict__ q_s,
                                                    float* __restrict__ q_d,
                                                    int* __restrict__ degs) {
    int bx = blockIdx.x;
    int tid = threadIdx.x;
    if (bx < 768) {
        int i = bx * 256 + tid;              // over 3*128*512
        if (i >= NLAYER * 128 * 512) return;
        int l = i >> 16;
        int rem = i & 65535;
        int jcol = rem >> 9;
        int p = rem & 511;
        int lanep = p >> 3, j8 = p & 7;
        int hp = j8 >> 1, bb = j8 & 1;
        int d = lanep * 2 + bb;
        wt2[i] = f2b(w_gat[(size_t)l * 65536 + (size_t)d * 512 + hp * 128 + jcol] * 0.25f);
    } else if (bx < 1152) {
        int bx2 = bx - 768;                  // over 3*128
        int l = bx2 >> 7, k = bx2 & 127;
        int hh_ = tid >> 6, lane = tid & 63;
        int d0 = lane * 2;
        size_t wb = (size_t)l * 65536 + (size_t)k * 512 + hh_ * 128;
        size_t ab = (size_t)l * 512 + hh_ * 128;
        float ps = w_gat[wb + d0] * a_src[ab + d0] + w_gat[wb + d0 + 1] * a_src[ab + d0 + 1];
        float pd = w_gat[wb + d0] * a_dst[ab + d0] + w_gat[wb + d0 + 1] * a_dst[ab + d0 + 1];
#pragma unroll
        for (int off = 32; off; off >>= 1) { ps += __shfl_xor(ps, off); pd += __shfl_xor(pd, off); }
        if (lane == 0) {
            q_s[(size_t)(l * 128 + k) * 4 + hh_] = ps;
            q_d[(size_t)(l * 128 + k) * 4 + hh_] = pd;
        }
    } else {
        int i0 = (bx - 1152) * 1024 + tid;
#pragma unroll
        for (int r = 0; r < 4; r++) {
            int i = i0 + r * 256;
            if (i < N_NODES) degs[i] = 0;
        }
    }
}

// ---------------------------------------------------------------------------
// prep: [0,2500) fat projection (8 nodes/block) + layer-0 alpha;
//       [2500, +333) fixed-capacity CSR scatter, 4 edges/thread.
// ---------------------------------------------------------------------------
__global__ __launch_bounds__(256) void prep_kernel(const float* __restrict__ x,
                                                   const float* __restrict__ w,
                                                   const float* __restrict__ b,
                                                   unsigned short* __restrict__ h_bf,
                                                   const float* __restrict__ q_s,
                                                   const float* __restrict__ q_d,
                                                   float4* __restrict__ als4,
                                                   float4* __restrict__ ald4,
                                                   const int* __restrict__ edge_index,
                                                   int* __restrict__ degs,
                                                   int* __restrict__ csr_src) {
    int bx = blockIdx.x;
    int tid = threadIdx.x;
    if (bx < 2500) {
        __shared__ float xr[8][F_NODE];
        __shared__ float vbuf[8][128];
        __shared__ float qs_t[512];
        __shared__ float qd_t[512];
        qs_t[tid] = q_s[tid]; qs_t[256 + tid] = q_s[256 + tid];
        qd_t[tid] = q_d[tid]; qd_t[256 + tid] = q_d[256 + tid];
        if (tid < 8 * F_NODE) {
            int nl = tid / F_NODE, k = tid % F_NODE;
            xr[nl][k] = x[(size_t)(bx * 8 + nl) * F_NODE + k];
        }
        __syncthreads();
        int d = tid & 127;
        int halfsel = tid >> 7;
#pragma unroll
        for (int p = 0; p < 4; p++) {
            int nl = p * 2 + halfsel;
            float acc = b[d];
#pragma unroll
            for (int k = 0; k < F_NODE; k++) acc += xr[nl][k] * w[k * DIM + d];
            float v = fmaxf(acc, 0.f);
            h_bf[(size_t)(bx * 8 + nl) * DIM + d] = f2b(v);
            vbuf[nl][d] = v;
        }
        __syncthreads();
        int wave = tid >> 6, lane = tid & 63;
#pragma unroll
        for (int t = 0; t < 2; t++) {
            int nl = wave * 2 + t;
            int n = bx * 8 + nl;
            float2 v2 = *(const float2*)&vbuf[nl][2 * lane];
            int k4 = 2 * lane * 4;
            float ps[4], pd[4];
#pragma unroll
            for (int hh_ = 0; hh_ < 4; hh_++) {
                ps[hh_] = v2.x * qs_t[k4 + hh_] + v2.y * qs_t[k4 + 4 + hh_];
                pd[hh_] = v2.x * qd_t[k4 + hh_] + v2.y * qd_t[k4 + 4 + hh_];
            }
#pragma unroll
            for (int off = 32; off; off >>= 1) {
#pragma unroll
                for (int hh_ = 0; hh_ < 4; hh_++) {
                    ps[hh_] += __shfl_xor(ps[hh_], off);
                    pd[hh_] += __shfl_xor(pd[hh_], off);
                }
            }
            if (lane == 0) {
                als4[n] = make_float4(ps[0], ps[1], ps[2], ps[3]);
                ald4[n] = make_float4(pd[0], pd[1], pd[2], pd[3]);
            }
        }
    } else {
        int base = (bx - 2500) * 1024;
#pragma unroll
        for (int k = 0; k < 4; k++) {
            int e = base + k * 256 + tid;
            if (e < E_TOTAL) {
                int s, d;
                if (e < N_EDGES) { s = edge_index[e]; d = edge_index[N_EDGES + e]; }
                else             { s = e - N_EDGES;   d = s; }
                int pos = atomicAdd(&degs[d], 1);
                if (pos < CSR_CAP) csr_src[d * CSR_CAP + pos] = s;
            }
        }
    }
}

// ---------------------------------------------------------------------------
// h-space aggregation (R15/R17-proven structure). Wave per node; lane owns
// feature pair (2*lane, 2*lane+1) for all 4 heads.
// - dedup exp: lane (4*edge+head) computes one exp chain per 4-edge batch;
//   weights distributed via __shfl with literal lane (v_readlane -> SGPR)
// - ls ownership: per-lane lsOwn, reduced once per node
// - index prefetch; f32x2 packed accumulate
// z layout: p = lane*8 + h*2 + b (uint4 store per lane).
// ---------------------------------------------------------------------------
template<int LYR>
__global__ __launch_bounds__(256) void agg2_kernel(const unsigned short* __restrict__ h_bf,
                                                   const float4* __restrict__ als4,
                                                   const float4* __restrict__ ald4,
                                                   const int* __restrict__ degs,
                                                   const int* __restrict__ csr_src,
                                                   unsigned short* __restrict__ z) {
    int wave = threadIdx.x >> 6, lane = threadIdx.x & 63;
    int n = blockIdx.x * 4 + wave;
    if (n >= N_NODES) return;

    int deg = degs[n];
    const int* __restrict__ srcp = csr_src + (size_t)n * CSR_CAP;
    const unsigned int* __restrict__ h32 = (const unsigned int*)h_bf;
    const float* __restrict__ als_f = (const float*)als4;
    float4 ad = ald4[n];

    int l4 = lane & 3;                   // head this lane's w-computation covers
    int le = (lane >> 2) & 3;            // edge-in-batch this lane covers
    float adh = (l4 == 0) ? ad.x : ((l4 == 1) ? ad.y : ((l4 == 2) ? ad.z : ad.w));

    f32x2 acc2[4] = {};
    float lsOwn = 0.f;

    int s0 = 0, s1 = 0, s2 = 0, s3 = 0;
    if (deg >= 4) { s0 = srcp[0]; s1 = srcp[1]; s2 = srcp[2]; s3 = srcp[3]; }
    int e = 0;
    for (; e + 4 <= deg; ) {
        int c0 = s0, c1 = s1, c2 = s2, c3 = s3;
        unsigned int hv0 = h32[(size_t)c0 * 64 + lane];
        unsigned int hv1 = h32[(size_t)c1 * 64 + lane];
        unsigned int hv2 = h32[(size_t)c2 * 64 + lane];
        unsigned int hv3 = h32[(size_t)c3 * 64 + lane];
        int se = (le == 0) ? c0 : ((le == 1) ? c1 : ((le == 2) ? c2 : c3));
        float a = als_f[(size_t)se * 4 + l4];
        int en = e + 4;
        if (en + 4 <= deg) { s0 = srcp[en]; s1 = srcp[en + 1]; s2 = srcp[en + 2]; s3 = srcp[en + 3]; }
        float v = a + adh;
        v = fmaxf(v, NEG_SLOPE * v);
        float w = __expf(fminf(v, 60.f));
        lsOwn += w;
        float wv[16];
#pragma unroll
        for (int j = 0; j < 16; j++) wv[j] = __shfl(w, j);
        unsigned int hv[4] = { hv0, hv1, hv2, hv3 };
#pragma unroll
        for (int j = 0; j < 4; j++) {
            f32x2 f; f.x = blo(hv[j]); f.y = bhi(hv[j]);
            acc2[0] += wv[j * 4 + 0] * f;
            acc2[1] += wv[j * 4 + 1] * f;
            acc2[2] += wv[j * 4 + 2] * f;
            acc2[3] += wv[j * 4 + 3] * f;
        }
        e = en;
    }
    float ls[4];
#pragma unroll
    for (int hh_ = 0; hh_ < 4; hh_++) {
        ls[hh_] = __shfl(lsOwn, hh_) + __shfl(lsOwn, 4 + hh_)
                + __shfl(lsOwn, 8 + hh_) + __shfl(lsOwn, 12 + hh_);
    }
    for (; e < deg; e++) {
        int s = srcp[e];
        float4 a4 = als4[s];
        unsigned int vv = h32[(size_t)s * 64 + lane];
        f32x2 f; f.x = blo(vv); f.y = bhi(vv);
#pragma unroll
        for (int hh_ = 0; hh_ < 4; hh_++) {
            float v = (&a4.x)[hh_] + (&ad.x)[hh_];
            v = (v > 0.f) ? v : NEG_SLOPE * v;
            float w = __expf(fminf(v, 60.f));
            ls[hh_] += w;
            acc2[hh_] += w * f;
        }
    }
    uint4 pb;
    unsigned int* pc = &pb.x;
#pragma unroll
    for (int hh_ = 0; hh_ < 4; hh_++) {
        float il = 1.f / ls[hh_];
        pc[hh_] = (unsigned)f2b(acc2[hh_].x * il) | ((unsigned)f2b(acc2[hh_].y * il) << 16);
    }
    *(uint4*)(z + (size_t)n * 512 + lane * 8) = pb;
}

// ---------------------------------------------------------------------------
// zgemm (templated per layer): out = z[M,512] @ wt2[128,512]^T, fused bias +
// LN + ReLU + bf16 residual + next-layer alpha. 64x128 tile, K in 4 chunks.
// ---------------------------------------------------------------------------
template<int LYR>
__global__ __launch_bounds__(256) void zgemm_kernel(const unsigned short* __restrict__ z,
                                                    const unsigned short* __restrict__ wt2_l,
                                                    const float* __restrict__ b_gat,
                                                    const float* __restrict__ ln_w,
                                                    const float* __restrict__ ln_b,
                                                    const unsigned short* __restrict__ hb_in,
                                                    unsigned short* __restrict__ hb_out,
                                                    const float* __restrict__ q_s_next,
                                                    const float* __restrict__ q_d_next,
                                                    float4* __restrict__ als4,
                                                    float4* __restrict__ ald4,
                                                    int M) {
    __shared__ __align__(16) unsigned short As[64 * 136];
    __shared__ __align__(16) unsigned short Bs[128 * 136];
    int tid = threadIdx.x;
    int m0 = blockIdx.x << 6;
    int wave = tid >> 6, lane = tid & 63;
    int lr = lane & 15, lg = lane >> 4;

    const uint4 zero4 = make_uint4(0, 0, 0, 0);
    f32x4 acc[8] = {};
    for (int kc = 0; kc < 4; kc++) {
#pragma unroll
        for (int p = 0; p < 4; p++) {        // A: 64 rows x 16 kg
            int i = p * 256 + tid;
            int row = i >> 4, kg = i & 15;
            int arow = m0 + row;
            uint4 av = (arow < M) ? *(const uint4*)(z + (size_t)arow * 512 + kc * 128 + kg * 8) : zero4;
            *(uint4*)&As[row * 136 + kg * 8] = av;
        }
#pragma unroll
        for (int p = 0; p < 8; p++) {        // B: 128 rows x 16 kg
            int i = p * 256 + tid;
            int row = i >> 4, kg = i & 15;
            uint4 bv = *(const uint4*)(wt2_l + (size_t)row * 512 + kc * 128 + kg * 8);
            *(uint4*)&Bs[row * 136 + kg * 8] = bv;
        }
        __syncthreads();
#pragma unroll
        for (int ks = 0; ks < 4; ks++) {
            bf16x8 af = *(const bf16x8*)&As[(wave * 16 + lr) * 136 + ks * 32 + lg * 8];
#pragma unroll
            for (int nt = 0; nt < 8; nt++) {
                bf16x8 bf_ = *(const bf16x8*)&Bs[(nt * 16 + lr) * 136 + ks * 32 + lg * 8];
                acc[nt] = __builtin_amdgcn_mfma_f32_16x16x32_bf16(af, bf_, acc[nt], 0, 0, 0);
            }
        }
        __syncthreads();
    }

    // epilogue: bias + LN + relu + residual (+ next-layer alpha)
    float bg[8], lnw[8], lnb[8];
#pragma unroll
    for (int nt = 0; nt < 8; nt++) {
        int col = nt * 16 + lr;
        bg[nt] = b_gat[col]; lnw[nt] = ln_w[col]; lnb[nt] = ln_b[col];
    }
    const bool do_alpha = (LYR + 1 < NLAYER);
    float4 qs4[8], qd4[8];
    if (do_alpha) {
#pragma unroll
        for (int nt = 0; nt < 8; nt++) {
            int col = nt * 16 + lr;
            qs4[nt] = *(const float4*)(q_s_next + (size_t)col * 4);
            qd4[nt] = *(const float4*)(q_d_next + (size_t)col * 4);
        }
    }
#pragma unroll
    for (int r = 0; r < 4; r++) {
        int row = m0 + wave * 16 + lg * 4 + r;
        bool valid = (row < M);
        float g[8];
        float s = 0.f;
#pragma unroll
        for (int nt = 0; nt < 8; nt++) { g[nt] = acc[nt][r] + bg[nt]; s += g[nt]; }
#pragma unroll
        for (int off = 1; off < 16; off <<= 1) s += __shfl_xor(s, off);
        float mu = s * (1.f / 128.f);
        float s2 = 0.f;
#pragma unroll
        for (int nt = 0; nt < 8; nt++) { float d = g[nt] - mu; s2 += d * d; }
#pragma unroll
        for (int off = 1; off < 16; off <<= 1) s2 += __shfl_xor(s2, off);
        float rstd = rsqrtf(s2 * (1.f / 128.f) + LN_EPS);
        float o[8];
#pragma unroll
        for (int nt = 0; nt < 8; nt++) {
            int col = nt * 16 + lr;
            float hv = valid ? b2f(hb_in[(size_t)row * 128 + col]) : 0.f;
            o[nt] = fmaxf((g[nt] - mu) * rstd * lnw[nt] + lnb[nt], 0.f) + hv;
            if (valid) hb_out[(size_t)row * 128 + col] = f2b(o[nt]);
        }
        if (do_alpha) {
            float ps[4] = {}, pd[4] = {};
#pragma unroll
            for (int nt = 0; nt < 8; nt++) {
                ps[0] += o[nt] * qs4[nt].x; pd[0] += o[nt] * qd4[nt].x;
                ps[1] += o[nt] * qs4[nt].y; pd[1] += o[nt] * qd4[nt].y;
                ps[2] += o[nt] * qs4[nt].z; pd[2] += o[nt] * qd4[nt].z;
                ps[3] += o[nt] * qs4[nt].w; pd[3] += o[nt] * qd4[nt].w;
            }
#pragma unroll
            for (int off = 1; off < 16; off <<= 1) {
#pragma unroll
                for (int hh_ = 0; hh_ < 4; hh_++) {
                    ps[hh_] += __shfl_xor(ps[hh_], off);
                    pd[hh_] += __shfl_xor(pd[hh_], off);
                }
            }
            if (lr == 0 && valid) {
                als4[row] = make_float4(ps[0], ps[1], ps[2], ps[3]);
                ald4[row] = make_float4(pd[0], pd[1], pd[2], pd[3]);
            }
        }
    }
}

// ---------------------------------------------------------------------------
// Fused pooling + tail per graph (h is bf16).
// ---------------------------------------------------------------------------
__device__ int lower_bound_dev(const int* a, int n, int v) {
    int lo = 0, hi = n;
    while (lo < hi) { int mid = (lo + hi) >> 1; if (a[mid] < v) lo = mid + 1; else hi = mid; }
    return lo;
}

__global__ __launch_bounds__(512) void pooltail_kernel(
    const unsigned short* __restrict__ h, const int* __restrict__ batch,
    const float* __restrict__ tda,
    const float* __restrict__ w_t1, const float* __restrict__ b_t1,
    const float* __restrict__ w_t2, const float* __restrict__ b_t2,
    const float* __restrict__ w_sh1, const float* __restrict__ b_sh1,
    const float* __restrict__ w_sh2, const float* __restrict__ b_sh2,
    const float* __restrict__ w_h1, const float* __restrict__ b_h1,
    const float* __restrict__ w_h2, const float* __restrict__ b_h2,
    float* __restrict__ out) {
    __shared__ float ssum[4][128];
    __shared__ float smax[4][128];
    __shared__ int bounds[2];
    __shared__ float comb[320];
    __shared__ float tr[F_TDA];
    __shared__ float t1[64];
    __shared__ float s1o[256];
    __shared__ float s2o[128];
    __shared__ float prods[NTASK * 64];
    int g = blockIdx.x, tid = threadIdx.x;

    if (tid < 2) bounds[tid] = lower_bound_dev(batch, N_NODES, g + tid);
    if (tid >= 2 && tid - 2 < F_TDA) tr[tid - 2] = tda[g * F_TDA + (tid - 2)];
    __syncthreads();
    int lo = bounds[0], hi = bounds[1];
    int q = tid >> 7, d = tid & 127;
    float s = 0.f, m = -1e30f;
    for (int i = lo + q; i < hi; i += 4) {
        float v = b2f(h[(size_t)i * DIM + d]);
        s += v; m = fmaxf(m, v);
    }
    ssum[q][d] = s; smax[q][d] = m;
    __syncthreads();
    if (tid < 128) {
        float S = ssum[0][d] + ssum[1][d] + ssum[2][d] + ssum[3][d];
        float M = fmaxf(fmaxf(smax[0][d], smax[1][d]), fmaxf(smax[2][d], smax[3][d]));
        int cnt = hi - lo;
        comb[d] = S / fmaxf((float)cnt, 1.f);
        comb[128 + d] = (cnt > 0) ? M : 0.f;
    } else if (tid >= 128 && tid < 192) {
        int j = tid - 128;
        float a = b_t1[j];
#pragma unroll
        for (int k = 0; k < F_TDA; k++) a += tr[k] * w_t1[k * 64 + j];
        t1[j] = fmaxf(a, 0.f);
    }
    __syncthreads();
    if (tid < 64) {
        float a = b_t2[tid];
#pragma unroll
        for (int k = 0; k < 64; k++) a += t1[k] * w_t2[k * 64 + tid];
        comb[256 + tid] = fmaxf(a, 0.f);
    }
    __syncthreads();
    if (tid < 256) {
        float a = b_sh1[tid];
        for (int k = 0; k < 320; k++) a += comb[k] * w_sh1[k * 256 + tid];
        s1o[tid] = fmaxf(a, 0.f);
    }
    __syncthreads();
    if (tid < 128) {
        float a = b_sh2[tid];
        for (int k = 0; k < 256; k++) a += s1o[k] * w_sh2[k * 128 + tid];
        s2o[tid] = fmaxf(a, 0.f);
    }
    __syncthreads();
    if (tid < NTASK * 64) {
        int t = tid >> 6, k = tid & 63;
        float a = b_h1[t * 64 + k];
#pragma unroll 16
        for (int dd = 0; dd < 128; dd++) a += s2o[dd] * w_h1[(size_t)t * 8192 + dd * 64 + k];
        prods[tid] = fmaxf(a, 0.f) * w_h2[t * 64 + k];
    }
    __syncthreads();
    if (tid < NTASK) {
        float p = b_h2[tid];
#pragma unroll 16
        for (int k = 0; k < 64; k++) p += prods[tid * 64 + k];
        out[tid * 256 + g] = p;
    }
}

// ---------------------------------------------------------------------------
extern "C" void kernel_launch(void* const* d_in, const int* in_sizes, int n_in,
                              void* d_out, int out_size, void* d_ws, size_t ws_size,
                              hipStream_t stream) {
    const float* x        = (const float*)d_in[0];
    const int*   edge_idx = (const int*)  d_in[1];
    const int*   batch    = (const int*)  d_in[2];
    const float* tda      = (const float*)d_in[3];
    const float* w_in     = (const float*)d_in[4];
    const float* b_in     = (const float*)d_in[5];
    const float* w_gat    = (const float*)d_in[6];
    const float* a_src    = (const float*)d_in[7];
    const float* a_dst    = (const float*)d_in[8];
    const float* b_gat    = (const float*)d_in[9];
    const float* ln_w     = (const float*)d_in[10];
    const float* ln_b     = (const float*)d_in[11];
    const float* w_tda1   = (const float*)d_in[12];
    const float* b_tda1   = (const float*)d_in[13];
    const float* w_tda2   = (const float*)d_in[14];
    const float* b_tda2   = (const float*)d_in[15];
    const float* w_sh1    = (const float*)d_in[16];
    const float* b_sh1    = (const float*)d_in[17];
    const float* w_sh2    = (const float*)d_in[18];
    const float* b_sh2    = (const float*)d_in[19];
    const float* w_h1     = (const float*)d_in[20];
    const float* b_h1     = (const float*)d_in[21];
    const float* w_h2     = (const float*)d_in[22];
    const float* b_h2     = (const float*)d_in[23];
    float* out = (float*)d_out;

    size_t off = 0;
    auto alloc = [&](size_t bytes) -> void* {
        void* p = (char*)d_ws + off;
        off += (bytes + 255) & ~(size_t)255;
        return p;
    };
    unsigned short* hb_a   = (unsigned short*)alloc((size_t)N_NODES * DIM * 2);
    unsigned short* hb_b   = (unsigned short*)alloc((size_t)N_NODES * DIM * 2);
    unsigned short* z      = (unsigned short*)alloc((size_t)N_NODES * 512 * 2);
    unsigned short* wt2    = (unsigned short*)alloc((size_t)NLAYER * 128 * 512 * 2);
    float*          q_s    = (float*)alloc((size_t)NLAYER * 128 * 4 * 4);
    float*          q_d    = (float*)alloc((size_t)NLAYER * 128 * 4 * 4);
    float4*         als4   = (float4*)alloc((size_t)N_NODES * 16);
    float4*         ald4   = (float4*)alloc((size_t)N_NODES * 16);
    int*            degs   = (int*)  alloc((size_t)N_NODES * 4);
    int*            csrsrc = (int*)  alloc((size_t)N_NODES * CSR_CAP * 4);

    // qprep also zeroes degs (blocks 1152..1171) — no separate memset
    qprep_kernel<<<1172, 256, 0, stream>>>(w_gat, a_src, a_dst, wt2, q_s, q_d, degs);

    int sb = (E_TOTAL + 1023) / 1024;   // 333
    prep_kernel<<<2500 + sb, 256, 0, stream>>>(x, w_in, b_in, hb_a, q_s, q_d,
                                               als4, ald4, edge_idx, degs, csrsrc);

    int ab = (N_NODES + 3) / 4;
    int gb = (N_NODES + 63) / 64;
    // layer 0: hb_a -> hb_b
    agg2_kernel<0><<<ab, 256, 0, stream>>>(hb_a, als4, ald4, degs, csrsrc, z);
    zgemm_kernel<0><<<gb, 256, 0, stream>>>(z, wt2,
        b_gat, ln_w, ln_b, hb_a, hb_b, q_s + 512, q_d + 512, als4, ald4, N_NODES);
    // layer 1: hb_b -> hb_a
    agg2_kernel<1><<<ab, 256, 0, stream>>>(hb_b, als4, ald4, degs, csrsrc, z);
    zgemm_kernel<1><<<gb, 256, 0, stream>>>(z, wt2 + 65536,
        b_gat + DIM, ln_w + DIM, ln_b + DIM, hb_b, hb_a, q_s + 1024, q_d + 1024,
        als4, ald4, N_NODES);
    // layer 2: hb_a -> hb_b
    agg2_kernel<2><<<ab, 256, 0, stream>>>(hb_a, als4, ald4, degs, csrsrc, z);
    zgemm_kernel<2><<<gb, 256, 0, stream>>>(z, wt2 + 131072,
        b_gat + 2 * DIM, ln_w + 2 * DIM, ln_b + 2 * DIM, hb_a, hb_b,
        nullptr, nullptr, als4, ald4, N_NODES);

    pooltail_kernel<<<N_GRAPHS, 512, 0, stream>>>(
        hb_b, batch, tda, w_tda1, b_tda1, w_tda2, b_tda2,
        w_sh1, b_sh1, w_sh2, b_sh2, w_h1, b_h1, w_h2, b_h2, out);
}